// Round 2
// baseline (989.219 us; speedup 1.0000x reference)
//
#include <hip/hip_runtime.h>
#include <hip/hip_bf16.h>

#define T_TOK 8192
#define HDIM  1024
#define FDIM  4096
#define NEXP  8

typedef __attribute__((ext_vector_type(8))) short short8;
typedef __attribute__((ext_vector_type(4))) float f32x4;
typedef unsigned short u16;
typedef unsigned int   u32;

// ---------------- ws layout (bytes) ----------------
#define XB_OFF    0ull                          // x bf16: T*H*2      = 16,777,216
#define W1B_OFF   (XB_OFF   + 16777216ull)      // w1 bf16: E*F*H*2   = 67,108,864
#define W3B_OFF   (W1B_OFF  + 67108864ull)
#define W2B_OFF   (W3B_OFF  + 67108864ull)
#define HBUF_OFF  (W2B_OFF  + 67108864ull)      // h bf16: 2T*F*2     = 134,217,728
#define CNT_OFF   (HBUF_OFF + 134217728ull)     // E ints
#define HOFF_OFF  (CNT_OFF  + 64ull)            // E+1 ints
#define TLIST_OFF (HOFF_OFF + 64ull)            // E*T ints  = 262,144
#define WLIST_OFF (TLIST_OFF + 262144ull)       // E*T float = 262,144
#define WS_NEED   (WLIST_OFF + 262144ull)

__device__ __forceinline__ u16 f2bf(float f) {           // RNE fp32 -> bf16
  u32 u = __float_as_uint(f);
  return (u16)((u + 0x7fffu + ((u >> 16) & 1u)) >> 16);
}

__device__ __forceinline__ void gl_lds16(const void* g, void* l) {
  __builtin_amdgcn_global_load_lds(
      (const __attribute__((address_space(1))) void*)g,
      (__attribute__((address_space(3))) void*)l, 16, 0, 0);
}

// ---------------- fp32 -> bf16 weight conversion (all 3 tensors, 1 launch) ----------------
__global__ __launch_bounds__(256) void convert3_kernel(
    const float* __restrict__ s0, const float* __restrict__ s1, const float* __restrict__ s2,
    u16* __restrict__ d0, u16* __restrict__ d1, u16* __restrict__ d2) {
  const int n4 = NEXP * FDIM * HDIM / 4;        // 8388608 = 2^23
  const int total = 3 * n4;
  int stride = gridDim.x * blockDim.x;
  for (int i = blockIdx.x * blockDim.x + threadIdx.x; i < total; i += stride) {
    int seg = i >> 23;
    int j = i & (n4 - 1);
    const float* s = seg == 0 ? s0 : (seg == 1 ? s1 : s2);
    u16* d = seg == 0 ? d0 : (seg == 1 ? d1 : d2);
    float4 v = ((const float4*)s)[j];
    u32 lo = (u32)f2bf(v.x) | ((u32)f2bf(v.y) << 16);
    u32 hi = (u32)f2bf(v.z) | ((u32)f2bf(v.w) << 16);
    ((uint2*)d)[j] = make_uint2(lo, hi);
  }
}

// ---------------- router: logits (fp32), top-2, lists; fused x->bf16 ----------------
__global__ __launch_bounds__(256) void router_kernel(
    const float* __restrict__ x, const float* __restrict__ gw,
    float* __restrict__ logits, u16* __restrict__ xb,
    int* __restrict__ counts, int* __restrict__ tlist, float* __restrict__ wlist) {
  const int wid = threadIdx.x >> 6, lane = threadIdx.x & 63;
  const int t = blockIdx.x * 4 + wid;           // one wave per token
  const float* xr = x + (size_t)t * HDIM + lane * 16;
  float4 xv[4];
#pragma unroll
  for (int q = 0; q < 4; ++q) xv[q] = ((const float4*)xr)[q];

  u32 pk[8];
#pragma unroll
  for (int q = 0; q < 4; ++q) {
    pk[q * 2 + 0] = (u32)f2bf(xv[q].x) | ((u32)f2bf(xv[q].y) << 16);
    pk[q * 2 + 1] = (u32)f2bf(xv[q].z) | ((u32)f2bf(xv[q].w) << 16);
  }
  u32* xbo = (u32*)(xb + (size_t)t * HDIM + lane * 16);
  ((uint4*)xbo)[0] = make_uint4(pk[0], pk[1], pk[2], pk[3]);
  ((uint4*)xbo)[1] = make_uint4(pk[4], pk[5], pk[6], pk[7]);

  float lg[NEXP];
#pragma unroll
  for (int e = 0; e < NEXP; ++e) {
    const float4* g = (const float4*)(gw + (size_t)e * HDIM + lane * 16);
    float s = 0.f;
#pragma unroll
    for (int q = 0; q < 4; ++q) {
      float4 gv = g[q];
      s += xv[q].x * gv.x + xv[q].y * gv.y + xv[q].z * gv.z + xv[q].w * gv.w;
    }
#pragma unroll
    for (int off = 32; off > 0; off >>= 1) s += __shfl_xor(s, off, 64);
    lg[e] = s;
  }
  if (lane == 0) {
    float* lo = logits + (size_t)t * NEXP;
#pragma unroll
    for (int e = 0; e < NEXP; ++e) lo[e] = lg[e];
    float v1 = -1e30f, v2 = -1e30f; int i1 = 0, i2 = 0;
#pragma unroll
    for (int e = 0; e < NEXP; ++e) {
      float le = lg[e];
      if (le > v1)      { v2 = v1; i2 = i1; v1 = le; i1 = e; }
      else if (le > v2) { v2 = le; i2 = e; }
    }
    float t2 = __expf(v2 - v1);
    float rs = 1.f / (1.f + t2);
    int p1 = atomicAdd(&counts[i1], 1);
    tlist[i1 * T_TOK + p1] = t; wlist[i1 * T_TOK + p1] = rs;
    int p2 = atomicAdd(&counts[i2], 1);
    tlist[i2 * T_TOK + p2] = t; wlist[i2 * T_TOK + p2] = t2 * rs;
  }
}

__global__ void prefix_kernel(const int* __restrict__ counts, int* __restrict__ hoff) {
  if (threadIdx.x == 0) {
    int s = 0;
    for (int e = 0; e < NEXP; ++e) { hoff[e] = s; s += counts[e]; }
    hoff[NEXP] = s;
  }
}

// ---------------- FFN1: h = silu(x@w1^T)*(x@w3^T), 256x128 tile, 8 waves ----------------
// T3-min schedule: sync -> ds_read all frags -> sync -> stage(next) -> MFMA cluster.
__global__ __launch_bounds__(512, 1) void ffn1_kernel(
    const u16* __restrict__ xb, const u16* __restrict__ w1b, const u16* __restrict__ w3b,
    u16* __restrict__ hbuf, const int* __restrict__ counts, const int* __restrict__ hoff,
    const int* __restrict__ tlist) {
  const int bid = blockIdx.x;
  const int e  = bid & 7;          // expert == XCD
  const int j  = bid >> 3;
  const int ct = j >> 5;           // F col tile 0..31 (128 wide)
  const int rt = j & 31;           // row tile (256 rows), fastest
  const int Ne = counts[e];
  if (rt * 256 >= Ne) return;

  __shared__ u16 Alds[256 * 64];   // 32 KB
  __shared__ u16 B1lds[128 * 64];  // 16 KB
  __shared__ u16 B3lds[128 * 64];  // 16 KB

  const int tid = threadIdx.x;
  const int wid = tid >> 6, lane = tid & 63;
  const int wr = wid >> 1, wc = wid & 1;      // 4M x 2N wave grid, 64x64/wave
  const int lr = lane & 15, lhi = lane >> 4;

  const int swcol = ((lane & 7) ^ ((lane >> 3) & 7)) * 8;  // inverse swizzle on SOURCE
  const int rowl  = tid >> 3;                              // 0..63 per round

  size_t aoff[4]; int ldsoA[4];
#pragma unroll
  for (int i = 0; i < 4; ++i) {
    int grow = rt * 256 + i * 64 + rowl;
    int gi = grow < Ne ? grow : Ne - 1;
    int tok = tlist[e * T_TOK + gi];
    aoff[i] = (size_t)tok * HDIM + swcol;
    ldsoA[i] = (i * 64 + wid * 8) * 64;      // wave-uniform LDS base (u16 units)
  }
  size_t b1off[2], b3off[2]; int ldsoB[2];
#pragma unroll
  for (int i = 0; i < 2; ++i) {
    int fr = ct * 128 + i * 64 + rowl;
    b1off[i] = ((size_t)e * FDIM + fr) * HDIM + swcol;
    b3off[i] = b1off[i];                      // same indexing, different tensor
    ldsoB[i] = (i * 64 + wid * 8) * 64;
  }

#define FFN1_STAGE(K0) do { \
  _Pragma("unroll") for (int i_ = 0; i_ < 4; ++i_) gl_lds16(xb  + aoff[i_]  + (K0), Alds  + ldsoA[i_]); \
  _Pragma("unroll") for (int i_ = 0; i_ < 2; ++i_) gl_lds16(w1b + b1off[i_] + (K0), B1lds + ldsoB[i_]); \
  _Pragma("unroll") for (int i_ = 0; i_ < 2; ++i_) gl_lds16(w3b + b3off[i_] + (K0), B3lds + ldsoB[i_]); \
} while (0)

  f32x4 acc1[4][4] = {}; f32x4 acc3[4][4] = {};
  FFN1_STAGE(0);

  for (int k0 = 0; k0 < HDIM; k0 += 64) {
    __syncthreads();                          // drains vmcnt -> tile ready
    short8 af[2][4], b1f[2][4], b3f[2][4];
#pragma unroll
    for (int kk = 0; kk < 2; ++kk) {
      const int swo = ((kk * 4 + lhi) ^ (lr & 7)) * 8;
#pragma unroll
      for (int m = 0; m < 4; ++m)
        af[kk][m] = *(const short8*)(Alds + (wr * 64 + m * 16 + lr) * 64 + swo);
#pragma unroll
      for (int n = 0; n < 4; ++n) {
        int o = (wc * 64 + n * 16 + lr) * 64 + swo;
        b1f[kk][n] = *(const short8*)(B1lds + o);
        b3f[kk][n] = *(const short8*)(B3lds + o);
      }
    }
    __syncthreads();                          // all reads retired (lgkmcnt drained)
    if (k0 + 64 < HDIM) FFN1_STAGE(k0 + 64);  // stage next tile; hides under MFMAs
    __builtin_amdgcn_s_setprio(1);
#pragma unroll
    for (int kk = 0; kk < 2; ++kk)
#pragma unroll
      for (int m = 0; m < 4; ++m)
#pragma unroll
        for (int n = 0; n < 4; ++n) {
          acc1[m][n] = __builtin_amdgcn_mfma_f32_16x16x32_bf16(af[kk][m], b1f[kk][n], acc1[m][n], 0, 0, 0);
          acc3[m][n] = __builtin_amdgcn_mfma_f32_16x16x32_bf16(af[kk][m], b3f[kk][n], acc3[m][n], 0, 0, 0);
        }
    __builtin_amdgcn_s_setprio(0);
  }

  const int hb = hoff[e];
  const int rbase = rt * 256 + wr * 64 + lhi * 4;
  const int cbase = ct * 128 + wc * 64 + lr;
#pragma unroll
  for (int m = 0; m < 4; ++m)
#pragma unroll
    for (int i = 0; i < 4; ++i) {
      int grow = rbase + m * 16 + i;
      if (grow < Ne) {
        size_t rowp = (size_t)(hb + grow) * FDIM + cbase;
#pragma unroll
        for (int n = 0; n < 4; ++n) {
          float a1 = acc1[m][n][i], a3 = acc3[m][n][i];
          float hv = (a1 / (1.f + __expf(-a1))) * a3;
          hbuf[rowp + n * 16] = f2bf(hv);
        }
      }
    }
#undef FFN1_STAGE
}

// ---------------- FFN2: out[tok] += w * (h @ w2^T), 256x128 tile, 8 waves ----------------
__global__ __launch_bounds__(512, 1) void ffn2_kernel(
    const u16* __restrict__ hbuf, const u16* __restrict__ w2b,
    float* __restrict__ out, const int* __restrict__ counts, const int* __restrict__ hoff,
    const int* __restrict__ tlist, const float* __restrict__ wlist) {
  const int bid = blockIdx.x;
  const int e  = bid & 7;
  const int j  = bid >> 3;
  const int ct = j >> 5;           // H col tile 0..7
  const int rt = j & 31;
  const int Ne = counts[e];
  if (rt * 256 >= Ne) return;
  const int hb = hoff[e];

  __shared__ u16 Alds[256 * 64];   // 32 KB
  __shared__ u16 Blds[128 * 64];   // 16 KB

  const int tid = threadIdx.x;
  const int wid = tid >> 6, lane = tid & 63;
  const int wr = wid >> 1, wc = wid & 1;
  const int lr = lane & 15, lhi = lane >> 4;

  const int swcol = ((lane & 7) ^ ((lane >> 3) & 7)) * 8;
  const int rowl  = tid >> 3;

  size_t aoff[4]; int ldsoA[4];
#pragma unroll
  for (int i = 0; i < 4; ++i) {
    int grow = rt * 256 + i * 64 + rowl;
    int gi = grow < Ne ? grow : Ne - 1;
    aoff[i] = (size_t)(hb + gi) * FDIM + swcol;
    ldsoA[i] = (i * 64 + wid * 8) * 64;
  }
  size_t boff[2]; int ldsoB[2];
#pragma unroll
  for (int i = 0; i < 2; ++i) {
    int hr = ct * 128 + i * 64 + rowl;
    boff[i] = ((size_t)e * HDIM + hr) * FDIM + swcol;
    ldsoB[i] = (i * 64 + wid * 8) * 64;
  }

#define FFN2_STAGE(K0) do { \
  _Pragma("unroll") for (int i_ = 0; i_ < 4; ++i_) gl_lds16(hbuf + aoff[i_] + (K0), Alds + ldsoA[i_]); \
  _Pragma("unroll") for (int i_ = 0; i_ < 2; ++i_) gl_lds16(w2b  + boff[i_] + (K0), Blds + ldsoB[i_]); \
} while (0)

  f32x4 acc[4][4] = {};
  FFN2_STAGE(0);

  for (int k0 = 0; k0 < FDIM; k0 += 64) {
    __syncthreads();
    short8 af[2][4], bf_[2][4];
#pragma unroll
    for (int kk = 0; kk < 2; ++kk) {
      const int swo = ((kk * 4 + lhi) ^ (lr & 7)) * 8;
#pragma unroll
      for (int m = 0; m < 4; ++m)
        af[kk][m] = *(const short8*)(Alds + (wr * 64 + m * 16 + lr) * 64 + swo);
#pragma unroll
      for (int n = 0; n < 4; ++n)
        bf_[kk][n] = *(const short8*)(Blds + (wc * 64 + n * 16 + lr) * 64 + swo);
    }
    __syncthreads();
    if (k0 + 64 < FDIM) FFN2_STAGE(k0 + 64);
    __builtin_amdgcn_s_setprio(1);
#pragma unroll
    for (int kk = 0; kk < 2; ++kk)
#pragma unroll
      for (int m = 0; m < 4; ++m)
#pragma unroll
        for (int n = 0; n < 4; ++n)
          acc[m][n] = __builtin_amdgcn_mfma_f32_16x16x32_bf16(af[kk][m], bf_[kk][n], acc[m][n], 0, 0, 0);
    __builtin_amdgcn_s_setprio(0);
  }

  const int rb = rt * 256 + wr * 64 + lhi * 4;
  const int cb = ct * 128 + wc * 64 + lr;
#pragma unroll
  for (int m = 0; m < 4; ++m)
#pragma unroll
    for (int i = 0; i < 4; ++i) {
      int grow = rb + m * 16 + i;
      if (grow < Ne) {
        int tok = tlist[e * T_TOK + grow];
        float wt = wlist[e * T_TOK + grow];
        float* op = out + (size_t)tok * HDIM + cb;
#pragma unroll
        for (int n = 0; n < 4; ++n)
          atomicAdd(op + n * 16, wt * acc[m][n][i]);
      }
    }
#undef FFN2_STAGE
}

extern "C" void kernel_launch(void* const* d_in, const int* in_sizes, int n_in,
                              void* d_out, int out_size, void* d_ws, size_t ws_size,
                              hipStream_t stream) {
  (void)in_sizes; (void)n_in; (void)out_size;
  if (ws_size < WS_NEED) return;

  const float* x  = (const float*)d_in[0];
  const float* gw = (const float*)d_in[1];
  const float* w1 = (const float*)d_in[2];
  const float* w3 = (const float*)d_in[3];
  const float* w2 = (const float*)d_in[4];
  float* out = (float*)d_out;
  float* logits = out + (size_t)T_TOK * HDIM;

  char* ws = (char*)d_ws;
  u16* xb    = (u16*)(ws + XB_OFF);
  u16* w1b   = (u16*)(ws + W1B_OFF);
  u16* w3b   = (u16*)(ws + W3B_OFF);
  u16* w2b   = (u16*)(ws + W2B_OFF);
  u16* hbuf  = (u16*)(ws + HBUF_OFF);
  int* counts = (int*)(ws + CNT_OFF);
  int* hoffp  = (int*)(ws + HOFF_OFF);
  int* tlist  = (int*)(ws + TLIST_OFF);
  float* wlist = (float*)(ws + WLIST_OFF);

  hipMemsetAsync(d_out, 0, (size_t)T_TOK * HDIM * sizeof(float), stream);
  hipMemsetAsync(counts, 0, NEXP * sizeof(int), stream);

  convert3_kernel<<<8192, 256, 0, stream>>>(w1, w3, w2, w1b, w3b, w2b);
  router_kernel<<<T_TOK / 4, 256, 0, stream>>>(x, gw, logits, xb, counts, tlist, wlist);
  prefix_kernel<<<1, 64, 0, stream>>>(counts, hoffp);
  ffn1_kernel<<<NEXP * 32 * 32, 512, 0, stream>>>(xb, w1b, w3b, hbuf, counts, hoffp, tlist);
  ffn2_kernel<<<NEXP * 8 * 32, 512, 0, stream>>>(hbuf, w2b, out, counts, hoffp, tlist, wlist);
}